// Round 6
// baseline (721.580 us; speedup 1.0000x reference)
//
#include <hip/hip_runtime.h>
#include <float.h>

typedef __attribute__((ext_vector_type(8))) short short8;
typedef __attribute__((ext_vector_type(4))) float f32x4;
typedef unsigned short u16;
typedef unsigned int u32;

#define N_ROWS 65536
#define K_CB   4096
#define D_DIM  256
#define TH     0.075f     // collect window: >= 2*worst-case bf16 score error (0.069)
#define FILT   0.08f      // resolve filter window (adds packing slop)
#define CAP    16
#define RR     8

// ws offsets (bytes) — total ~672 KB (proven available)
#define WS_COUNTER 0
#define WS_ESQ     256
#define WS_IDX     (WS_ESQ + K_CB*4)
#define WS_FLAG    (WS_IDX + N_ROWS*4)
#define WS_PART    (WS_FLAG + N_ROWS*4)
#define NUM_OUT_BLOCKS 16384

// d_out scratch offsets (bytes) — inside quantized region, overwritten by output_kernel
#define SC_EHP  256
#define SC_CAND (SC_EHP + K_CB*D_DIM*2)          // +2 MB
#define SC_CNT  (SC_CAND + N_ROWS*CAP*4)         // +4 MB

// ---------- helpers ----------
__device__ __forceinline__ u16 f2bf(float x) {
  unsigned int u = __float_as_uint(x);
  unsigned int r = (u + 0x7fffu + ((u >> 16) & 1u)) >> 16;
  return (u16)r;
}
__device__ __forceinline__ u32 flip32(u32 u) {
  return u ^ ((u & 0x80000000u) ? 0xFFFFFFFFu : 0x80000000u);
}
__device__ __forceinline__ float unflip20(u32 p) {
  u32 v = p & 0xFFFFF000u;
  u32 u = (v & 0x80000000u) ? (v ^ 0x80000000u) : ~v;
  return __uint_as_float(u);
}
// np-exact final combine: fl( fl(zsq+esq) - fl(2*dot) )
__device__ __forceinline__ float np_score(float zsq, float ek, float dot) {
#pragma clang fp contract(off)
  float t1 = zsq + ek;
  float t2 = 2.0f * dot;
  return t1 - t2;
}

// ---------- numpy-emulated pairwise sum of squares ----------
__device__ __forceinline__ float np_sum128_sq(const float* p) {
#pragma clang fp contract(off)
  float r0 = p[0]*p[0], r1 = p[1]*p[1], r2 = p[2]*p[2], r3 = p[3]*p[3];
  float r4 = p[4]*p[4], r5 = p[5]*p[5], r6 = p[6]*p[6], r7 = p[7]*p[7];
  for (int i = 8; i < 128; i += 8) {
    r0 += p[i+0]*p[i+0]; r1 += p[i+1]*p[i+1];
    r2 += p[i+2]*p[i+2]; r3 += p[i+3]*p[i+3];
    r4 += p[i+4]*p[i+4]; r5 += p[i+5]*p[i+5];
    r6 += p[i+6]*p[i+6]; r7 += p[i+7]*p[i+7];
  }
  return ((r0+r1)+(r2+r3))+((r4+r5)+(r6+r7));
}
__device__ __forceinline__ float np_sumsq256(const float* p) {
#pragma clang fp contract(off)
  float a = np_sum128_sq(p);
  float b = np_sum128_sq(p + 128);
  return a + b;
}

__global__ __launch_bounds__(256) void esq_np_kernel(const float* __restrict__ cb,
                                                     float* __restrict__ esq) {
  const int k = blockIdx.x * 256 + threadIdx.x;
  esq[k] = np_sumsq256(cb + (size_t)k * D_DIM);
}

// ---------- codebook bf16-hi, MFMA-A-fragment-permuted ----------
// layout (elems): [chunk 128][s 8][lq 4][code 32][j 8]
__global__ __launch_bounds__(256) void esplit_hi_perm(const float* __restrict__ cb,
                                                      u16* __restrict__ ehp) {
  const int g  = blockIdx.x * 256 + threadIdx.x;   // k*32 + d8
  const int k  = g >> 5, d8 = g & 31;
  const int c  = k >> 5, code = k & 31;
  const int s  = d8 >> 2, lq = d8 & 3;
  const float* src = cb + (size_t)k * D_DIM + d8 * 8;
  float4 f0 = *(const float4*)src;
  float4 f1 = *(const float4*)(src + 4);
  float f[8] = {f0.x,f0.y,f0.z,f0.w,f1.x,f1.y,f1.z,f1.w};
  short8 h;
  #pragma unroll
  for (int j = 0; j < 8; ++j) h[j] = (short)f2bf(f[j]);
  *(short8*)(ehp + (size_t)c*8192 + s*1024 + lq*256 + code*8) = h;
}

// ---------- fused coarse-min + candidate collect ----------
// 512 thr = 8 waves (rg=w>>1 in [0,4), cg=w&1). Wave: 64 z-rows persistent as
// MFMA B-operand (bz[4][8], 128 VGPR); codes stream as A from LDS (2 reads per
// 8 MFMAs). Chunk = 32 codes per cg-wave (iteration covers 64). Exact running
// per-row min via in-lane + shfl16/32 + cross-cg LDS merge; collect codes
// within TH of the running min (packed score|code) one iteration delayed.
__global__ __launch_bounds__(512, 2) void coarse_collect_kernel(
    const float* __restrict__ z, const u16* __restrict__ ehp,
    const float* __restrict__ esq, u32* __restrict__ cand,
    u32* __restrict__ cnt) {
  __shared__ u16 alds[16384];          // 32 KB: [cg 2][s 8][lq 4][code 32][j 8]
  __shared__ float rmbuf[2][256][2];   // 4 KB
  const int t = threadIdx.x;
  const int w = t >> 6, l = t & 63;
  const int rg = w >> 1, cg = w & 1;
  const int l16 = l & 15, lq = l >> 4;
  const int rowbase = blockIdx.x * 256 + rg * 64;

  // persistent z fragments (B side): zrow = rowbase + n*16 + l16, k = lq*8+j
  short8 bz[4][8];
  #pragma unroll
  for (int n = 0; n < 4; ++n) {
    const float* zp = z + (size_t)(rowbase + n*16 + l16) * D_DIM + lq*8;
    #pragma unroll
    for (int s = 0; s < 8; ++s) {
      float4 f0 = *(const float4*)(zp + s*32);
      float4 f1 = *(const float4*)(zp + s*32 + 4);
      float f[8] = {f0.x,f0.y,f0.z,f0.w,f1.x,f1.y,f1.z,f1.w};
      short8 h;
      #pragma unroll
      for (int j = 0; j < 8; ++j) h[j] = (short)f2bf(f[j]);
      bz[n][s] = h;
    }
  }

  f32x4 acc[2][4];
  #pragma unroll
  for (int tt = 0; tt < 2; ++tt)
    #pragma unroll
    for (int n = 0; n < 4; ++n) acc[tt][n] = (f32x4){0.f,0.f,0.f,0.f};
  float rm[4] = {FLT_MAX, FLT_MAX, FLT_MAX, FLT_MAX};
  float esqv[8];

  const char* ehb = (const char*)ehp;
  uint4 stg[4];
  #pragma unroll
  for (int r = 0; r < 4; ++r)
    stg[r] = *(const uint4*)(ehb + r*8192 + t*16);

  for (int cc = 0; cc < 64; ++cc) {
    __syncthreads();   // prev MFMA reads of alds done; rmbuf[prev] ready
    if (cc > 0) {
      // merge cross-cg row mins, then collect chunk cc-1 from live acc
      #pragma unroll
      for (int n = 0; n < 4; ++n) {
        const float* rb = &rmbuf[(cc-1)&1][rg*64 + n*16 + l16][0];
        rm[n] = fminf(rm[n], fminf(rb[0], rb[1]));
      }
      const int chp = (cc-1)*2 + cg;
      #pragma unroll
      for (int tt = 0; tt < 2; ++tt)
        #pragma unroll
        for (int n = 0; n < 4; ++n)
          #pragma unroll
          for (int r = 0; r < 4; ++r) {
            float sc = fmaf(-2.0f, acc[tt][n][r], esqv[tt*4+r]);
            if (sc < rm[n] + TH) {
              int row  = rowbase + n*16 + l16;
              int code = chp*32 + tt*16 + lq*4 + r;
              u32 pk = (flip32(__float_as_uint(sc)) & 0xFFFFF000u) | (u32)code;
              u32 pos = atomicAdd(&cnt[row], 1u);
              if (pos < CAP) cand[(size_t)row*CAP + pos] = pk;
            }
            acc[tt][n][r] = 0.0f;
          }
    }
    // write staged chunk-pair cc, then issue loads for cc+1
    {
      char* lb = (char*)alds;
      #pragma unroll
      for (int r = 0; r < 4; ++r) *(uint4*)(lb + r*8192 + t*16) = stg[r];
    }
    if (cc < 63) {
      #pragma unroll
      for (int r = 0; r < 4; ++r)
        stg[r] = *(const uint4*)(ehb + (size_t)(cc+1)*32768 + r*8192 + t*16);
    }
    __syncthreads();   // alds ready

    const int ch = cc*2 + cg;
    #pragma unroll
    for (int tt = 0; tt < 2; ++tt)
      #pragma unroll
      for (int r = 0; r < 4; ++r)
        esqv[tt*4+r] = esq[ch*32 + tt*16 + lq*4 + r];

    const char* ab = (const char*)alds + cg*16384;
    #pragma unroll
    for (int s = 0; s < 8; ++s) {
      short8 a0 = *(const short8*)(ab + s*2048 + lq*512 + l16*16);
      short8 a1 = *(const short8*)(ab + s*2048 + lq*512 + 256 + l16*16);
      #pragma unroll
      for (int n = 0; n < 4; ++n) {
        acc[0][n] = __builtin_amdgcn_mfma_f32_16x16x32_bf16(a0, bz[n][s], acc[0][n], 0,0,0);
        acc[1][n] = __builtin_amdgcn_mfma_f32_16x16x32_bf16(a1, bz[n][s], acc[1][n], 0,0,0);
      }
    }
    // phase A: per-row chunk-min (in-lane over 8 codes, then xor16/xor32)
    #pragma unroll
    for (int n = 0; n < 4; ++n) {
      float m = FLT_MAX;
      #pragma unroll
      for (int tt = 0; tt < 2; ++tt)
        #pragma unroll
        for (int r = 0; r < 4; ++r)
          m = fminf(m, fmaf(-2.0f, acc[tt][n][r], esqv[tt*4+r]));
      m = fminf(m, __shfl_xor(m, 16));
      m = fminf(m, __shfl_xor(m, 32));
      if (lq == 0) rmbuf[cc&1][rg*64 + n*16 + l16][cg] = m;
    }
  }
  // final phase B (cc = 63)
  __syncthreads();
  {
    #pragma unroll
    for (int n = 0; n < 4; ++n) {
      const float* rb = &rmbuf[1][rg*64 + n*16 + l16][0];
      rm[n] = fminf(rm[n], fminf(rb[0], rb[1]));
    }
    const int chp = 126 + cg;
    #pragma unroll
    for (int tt = 0; tt < 2; ++tt)
      #pragma unroll
      for (int n = 0; n < 4; ++n)
        #pragma unroll
        for (int r = 0; r < 4; ++r) {
          float sc = fmaf(-2.0f, acc[tt][n][r], esqv[tt*4+r]);
          if (sc < rm[n] + TH) {
            int row  = rowbase + n*16 + l16;
            int code = chp*32 + tt*16 + lq*4 + r;
            u32 pk = (flip32(__float_as_uint(sc)) & 0xFFFFF000u) | (u32)code;
            u32 pos = atomicAdd(&cnt[row], 1u);
            if (pos < CAP) cand[(size_t)row*CAP + pos] = pk;
          }
        }
  }
}

// ---------- resolve: np-exact scoring of shortlist, first-index argmin ----------
__global__ __launch_bounds__(256) void resolve_kernel(
    const float* __restrict__ z, const float* __restrict__ cb,
    const float* __restrict__ esq, const u32* __restrict__ cand,
    const u32* __restrict__ cnt, int* __restrict__ idx,
    int* __restrict__ flag, u32* __restrict__ counter) {
  __shared__ float zs[16][256];
  __shared__ float sco[16][16];
  __shared__ int   scd[16][16];
  __shared__ u32   pm[16];
  const int t = threadIdx.x;
  const int r = t >> 4, s = t & 15;
  const int row0 = blockIdx.x * 16;
  #pragma unroll
  for (int q = 0; q < 4; ++q) {
    int g = t + 256*q;
    ((float4*)&zs[0][0])[g] = ((const float4*)(z + (size_t)row0 * D_DIM))[g];
  }
  __syncthreads();
  const int row = row0 + r;
  const u32 n = cnt[row];
  const int m = (n < CAP) ? (int)n : CAP;
  if (s == 0) {
    u32 p = 0xFFFFFFFFu;
    for (int i = 0; i < m; ++i) p = min(p, cand[(size_t)row*CAP + i]);
    pm[r] = p;
  }
  __syncthreads();
  const float smin = unflip20(pm[r]);
  float myscore = FLT_MAX; int mycode = 0x7FFFFFFF;
  if (s < m) {
    u32 pk = cand[(size_t)row*CAP + s];
    if (unflip20(pk) <= smin + FILT) {
      int code = (int)(pk & 0xFFFu);
      float zsq = np_sumsq256(&zs[r][0]);
      const float4* e4 = (const float4*)(cb + (size_t)code * D_DIM);
      float acc = 0.0f;
      for (int dq = 0; dq < 64; ++dq) {
        float4 ev = e4[dq];
        float4 zv = *(const float4*)&zs[r][dq*4];
        acc = __fmaf_rn(zv.x, ev.x, acc);
        acc = __fmaf_rn(zv.y, ev.y, acc);
        acc = __fmaf_rn(zv.z, ev.z, acc);
        acc = __fmaf_rn(zv.w, ev.w, acc);
      }
      myscore = np_score(zsq, esq[code], acc);
      mycode = code;
    }
  }
  sco[r][s] = myscore; scd[r][s] = mycode;
  __syncthreads();
  if (s == 0) {
    if (n > CAP) {
      idx[row] = 0;
      u32 p = atomicAdd(counter, 1u);
      flag[p] = row;
    } else {
      float bs = sco[r][0]; int bc = scd[r][0];
      for (int i = 1; i < m; ++i) {
        float os = sco[r][i]; int oc = scd[r][i];
        if (os < bs || (os == bs && oc < bc)) { bs = os; bc = oc; }
      }
      idx[row] = bc;
    }
  }
}

// ---------- full np-exact rescan for overflow rows ----------
__global__ __launch_bounds__(256) void refine_np_kernel(
    const float* __restrict__ z, const float* __restrict__ cb,
    const float* __restrict__ esq, int* __restrict__ idx_out,
    const int* __restrict__ flag, const u32* __restrict__ counter) {
  __shared__ float zrow[RR][D_DIM];
  __shared__ float zsq[RR];
  __shared__ float rbest[256];
  __shared__ int   rbidx[256];
  const int t = threadIdx.x;
  const u32 cntv = *counter;
  const u32 ngroups = (cntv + RR - 1) / RR;
  for (u32 g = blockIdx.x; g < ngroups; g += gridDim.x) {
    __syncthreads();
    const int nr = (int)min((u32)RR, cntv - g*RR);
    #pragma unroll
    for (int r = 0; r < RR; ++r) {
      int fi = (int)(g*RR) + ((r < nr) ? r : 0);
      int row = flag[fi];
      zrow[r][t] = z[(size_t)row * D_DIM + t];
    }
    __syncthreads();
    if (t < RR) zsq[t] = np_sumsq256(&zrow[t][0]);
    __syncthreads();
    float best[RR]; int bidx[RR];
    #pragma unroll
    for (int r = 0; r < RR; ++r) { best[r] = FLT_MAX; bidx[r] = 0x7fffffff; }
    for (int mblk = 0; mblk < K_CB / 256; ++mblk) {
      const int k = mblk*256 + t;
      const float4* e4 = (const float4*)(cb + (size_t)k * D_DIM);
      float acc[RR];
      #pragma unroll
      for (int r = 0; r < RR; ++r) acc[r] = 0.0f;
      for (int dq = 0; dq < D_DIM/4; ++dq) {
        float4 ev = e4[dq];
        #pragma unroll
        for (int r = 0; r < RR; ++r) {
          acc[r] = __fmaf_rn(zrow[r][dq*4+0], ev.x, acc[r]);
          acc[r] = __fmaf_rn(zrow[r][dq*4+1], ev.y, acc[r]);
          acc[r] = __fmaf_rn(zrow[r][dq*4+2], ev.z, acc[r]);
          acc[r] = __fmaf_rn(zrow[r][dq*4+3], ev.w, acc[r]);
        }
      }
      const float ek = esq[k];
      #pragma unroll
      for (int r = 0; r < RR; ++r) {
        float sc = np_score(zsq[r], ek, acc[r]);
        if (sc < best[r]) { best[r] = sc; bidx[r] = k; }
      }
    }
    for (int r = 0; r < RR; ++r) {
      __syncthreads();
      rbest[t] = best[r]; rbidx[t] = bidx[r];
      __syncthreads();
      for (int off = 128; off > 0; off >>= 1) {
        if (t < off) {
          float ob = rbest[t+off]; int oi = rbidx[t+off];
          if (ob < rbest[t] || (ob == rbest[t] && oi < rbidx[t])) {
            rbest[t] = ob; rbidx[t] = oi;
          }
        }
        __syncthreads();
      }
      if (t == 0 && r < nr) idx_out[flag[g*RR + r]] = rbidx[0];
    }
  }
}

// ---------- gather + outputs + loss ----------
__global__ __launch_bounds__(256) void output_kernel(
    const float4* __restrict__ z4, const float4* __restrict__ cb4,
    const int* __restrict__ idx_out, float* __restrict__ out,
    double* __restrict__ partials) {
  const int g  = blockIdx.x * 256 + threadIdx.x;
  const int n  = g >> 6;
  const int dq = g & 63;
  const int id = idx_out[n];
  float4 q  = cb4[(size_t)id * (D_DIM/4) + dq];
  float4 zv = z4[(size_t)n  * (D_DIM/4) + dq];
  float dx = q.x - zv.x, dy = q.y - zv.y, dz = q.z - zv.z, dw = q.w - zv.w;
  double psum = (double)dx*dx + (double)dy*dy + (double)dz*dz + (double)dw*dw;
  size_t base = 1 + (size_t)n * D_DIM + (size_t)dq * 4;
  out[base+0] = q.x; out[base+1] = q.y; out[base+2] = q.z; out[base+3] = q.w;
  if (dq == 0) out[1 + (size_t)N_ROWS*D_DIM + n] = (float)id;
  __shared__ double sred[256];
  sred[threadIdx.x] = psum;
  __syncthreads();
  for (int off = 128; off > 0; off >>= 1) {
    if (threadIdx.x < off) sred[threadIdx.x] += sred[threadIdx.x + off];
    __syncthreads();
  }
  if (threadIdx.x == 0) partials[blockIdx.x] = sred[0];
}

__global__ __launch_bounds__(256) void loss_kernel(const double* __restrict__ partials,
                                                   float* __restrict__ out) {
  const int t = threadIdx.x;
  double s = 0.0;
  for (int m = 0; m < NUM_OUT_BLOCKS/256; ++m) s += partials[t + 256*m];
  __shared__ double sred[256];
  sred[t] = s;
  __syncthreads();
  for (int off = 128; off > 0; off >>= 1) {
    if (t < off) sred[t] += sred[t + off];
    __syncthreads();
  }
  if (t == 0) out[0] = (float)(1.25 * sred[0] / ((double)N_ROWS * (double)D_DIM));
}

extern "C" void kernel_launch(void* const* d_in, const int* in_sizes, int n_in,
                              void* d_out, int out_size, void* d_ws, size_t ws_size,
                              hipStream_t stream) {
  const float* z  = (const float*)d_in[0];
  const float* cb = (const float*)d_in[1];
  float* out = (float*)d_out;
  char*  ws  = (char*)d_ws;
  char*  ob  = (char*)d_out;

  // big scratch lives in the d_out quantized region (overwritten by output_kernel)
  u16* ehp  = (u16*)(ob + SC_EHP);
  u32* cand = (u32*)(ob + SC_CAND);
  u32* cnt  = (u32*)(ob + SC_CNT);

  u32*    counter  = (u32*)   (ws + WS_COUNTER);
  float*  esq      = (float*) (ws + WS_ESQ);
  int*    idx      = (int*)   (ws + WS_IDX);
  int*    flag     = (int*)   (ws + WS_FLAG);
  double* partials = (double*)(ws + WS_PART);

  (void)hipMemsetAsync(ws, 0, 16, stream);
  (void)hipMemsetAsync(cnt, 0, N_ROWS*4, stream);

  esq_np_kernel<<<K_CB/256, 256, 0, stream>>>(cb, esq);
  esplit_hi_perm<<<(K_CB*(D_DIM/8))/256, 256, 0, stream>>>(cb, ehp);
  coarse_collect_kernel<<<N_ROWS/256, 512, 0, stream>>>(z, ehp, esq, cand, cnt);
  resolve_kernel<<<N_ROWS/16, 256, 0, stream>>>(z, cb, esq, cand, cnt, idx, flag, counter);
  refine_np_kernel<<<256, 256, 0, stream>>>(z, cb, esq, idx, flag, counter);
  output_kernel<<<NUM_OUT_BLOCKS, 256, 0, stream>>>((const float4*)z, (const float4*)cb,
                                                    idx, out, partials);
  loss_kernel<<<1, 256, 0, stream>>>(partials, out);
}